// Round 5
// baseline (48.887 us; speedup 1.0000x reference)
//
#include <hip/hip_runtime.h>
#include <hip/hip_fp16.h>

// Problem constants (match reference)
#define BATCH 32
#define CH    2
#define HH    224
#define WW    224
#define PP    4096
#define NN    256
#define SPLIT 32
#define TILE  (PP / SPLIT)   // 128 points per block
#define TILE2 (TILE / 2)     // 64 packed point-pairs

// ws layout (fast path): [0,64K) float2 Y[B*N]; [64K,96K) part[1024*4] dbl;
// [96K] uint counter.
#define WS_Y_OFF    0
#define WS_PART_OFF (64 * 1024)
#define WS_CNT_OFF  (96 * 1024)
#define WS_NEED     (96 * 1024 + 64)

// Packed vote-point pair: (u0,u1),(v0,v1),(-c0,-c1) in f16, padded to 16B so
// the vote loop reads one ds_read_b128 per TWO points. c = py*u + px*v, so
// agree = sign(yy*u + yx*v - c)  (normalization can't flip the sign).
struct alignas(16) PtPack { __half2 u, v, nc, pad; };

// ---- shared solve: 2x2 pinv (f64, matches jnp.linalg.pinv semantics) ----
__device__ inline float2 solve_pair(const float* __restrict__ uvb,
                                    const int* __restrict__ ptsb,
                                    const int* __restrict__ pairb, int n)
{
    const int2 pr = *(const int2*)(pairb + n * 2);
    const int2 p0 = *(const int2*)(ptsb + pr.x * 2);
    const int2 p1 = *(const int2*)(ptsb + pr.y * 2);
    const int y0 = p0.x, x0 = p0.y;
    const int y1 = p1.x, x1 = p1.y;

    const float u0a = uvb[y0 * WW + x0];                 // uv[0] at pt0
    const float u0b = uvb[HH * WW + y0 * WW + x0];       // uv[1] at pt0
    const float u1a = uvb[y1 * WW + x1];                 // uv[0] at pt1
    const float u1b = uvb[HH * WW + y1 * WW + x1];       // uv[1] at pt1

    const double a00 = (double)u0a, a01 = -(double)u1a;
    const double a10 = (double)u0b, a11 = -(double)u1b;
    const double b0 = (double)(y1 - y0), b1 = (double)(x1 - x0);
    const double det = a00 * a11 - a01 * a10;
    const double frob2 = a00 * a00 + a01 * a01 + a10 * a10 + a11 * a11;

    double t0;
    if (fabs(det) > 1e-12 * frob2) {
        t0 = (b0 * a11 - b1 * a01) / det;          // first row of A^{-1} b
    } else if (frob2 > 0.0) {
        t0 = (a00 * b0 + a10 * b1) / frob2;        // rank-1 pinv: A^T b / ||A||_F^2
    } else {
        t0 = 0.0;
    }
    return make_float2((float)(t0 * (double)u0a + (double)y0),   // row
                       (float)(t0 * (double)u0b + (double)x0));  // col
}

// Kernel 1: solve every (b,n) ONCE. 32 blocks x 256 threads, coalesced
// float2 output. Also resets the last-block-done counter (stream order
// guarantees visibility to kernel 2).
__global__ __launch_bounds__(256)
void hough_solve(const float* __restrict__ uv,
                 const int* __restrict__ pts,
                 const int* __restrict__ pair,
                 float2* __restrict__ yv,
                 unsigned* __restrict__ cnt)
{
    const int b = blockIdx.x;
    const int t = threadIdx.x;
    const float* uvb = uv + (size_t)b * CH * HH * WW;
    yv[b * NN + t] = solve_pair(uvb, pts + b * PP * 2, pair + b * NN * 2, t);
    if (b == 0 && t == 0)
        __hip_atomic_store(cnt, 0u, __ATOMIC_RELAXED, __HIP_MEMORY_SCOPE_AGENT);
}

// Kernel 2: one block per (batch, point-tile). 256 threads, one per pair n.
//   1. stage TILE points as f16 PtPacks in LDS
//   2. read Y (coalesced 8B), rescale into f16-safe range
//   3. packed-f16 vote, sign-bit counting
//   4. wave-shuffle reduce -> per-block partial
//   5. last-block-done: final combine + output write (deterministic math)
__global__ __launch_bounds__(256, 4)
void hough_vote(const float* __restrict__ uv,
                const int* __restrict__ pts,
                const float2* __restrict__ yv,
                double* __restrict__ part,
                unsigned* __restrict__ cnt,
                float* __restrict__ out)
{
    const int blk = blockIdx.x;
    const int b = blk / SPLIT;
    const int s = blk % SPLIT;
    const int t = threadIdx.x;   // n = t

    const float* uvb = uv + (size_t)b * CH * HH * WW;
    const int* ptsb = pts + b * PP * 2;

    // ---- stage this block's point tile in LDS (f16-packed, 2 pts / 16B) ----
    __shared__ PtPack tile[TILE2];
    if (t < TILE2) {
        const int p = s * TILE + 2 * t;
        const int4 pp = *(const int4*)(ptsb + p * 2);   // (y0,x0,y1,x1), 16B
        const float u0 = uvb[pp.x * WW + pp.y];
        const float v0 = uvb[HH * WW + pp.x * WW + pp.y];
        const float u1 = uvb[pp.z * WW + pp.w];
        const float v1 = uvb[HH * WW + pp.z * WW + pp.w];
        const float c0 = (float)pp.x * u0 + (float)pp.y * v0;
        const float c1 = (float)pp.z * u1 + (float)pp.w * v1;
        PtPack pk;
        pk.u  = __floats2half2_rn(u0, u1);
        pk.v  = __floats2half2_rn(v0, v1);
        pk.nc = __floats2half2_rn(-c0, -c1);
        pk.pad = __floats2half2_rn(0.0f, 0.0f);
        tile[t] = pk;
    }

    // ---- read precomputed Y, scale (yy, yx, 1) into f16-safe range ----
    const float2 Yn = yv[b * NN + t];
    const float yy = Yn.x, yx = Yn.y;
    const float maxab = fmaxf(fabsf(yy), fabsf(yx));
    const float sc = (maxab > 1024.0f) ? (1024.0f / maxab) : 1.0f;
    const __half2 yy2 = __float2half2_rn(yy * sc);
    const __half2 yx2 = __float2half2_rn(yx * sc);
    const __half2 sc2 = __float2half2_rn(sc);

    __syncthreads();

    // ---- voting: packed f16, 2 points per iteration, sign-bit counting ----
    unsigned negs = 0u;
    #pragma unroll 4
    for (int j = 0; j < TILE2; ++j) {
        const PtPack q = tile[j];                  // broadcast ds_read_b128
        __half2 d = __hmul2(yy2, q.u);
        d = __hfma2(yx2, q.v, d);
        d = __hfma2(sc2, q.nc, d);
        unsigned ub;
        __builtin_memcpy(&ub, &d, 4);
        negs += (ub >> 15) & 0x00010001u;          // sign bits of both halves
    }
    const int cw = TILE - (int)(negs & 0xFFFFu) - (int)(negs >> 16);

    // ---- deterministic reduction of (w*Yy, w*Yx, w) ----
    double wy = (double)cw * (double)yy;
    double wx = (double)cw * (double)yx;
    double ww = (double)cw;
    #pragma unroll
    for (int off = 32; off > 0; off >>= 1) {
        wy += __shfl_down(wy, off);
        wx += __shfl_down(wx, off);
        ww += __shfl_down(ww, off);
    }

    __shared__ double red[4 * 3];
    __shared__ int lastFlag;
    const int wid = t >> 6;
    if ((t & 63) == 0) {
        red[wid * 3 + 0] = wy;
        red[wid * 3 + 1] = wx;
        red[wid * 3 + 2] = ww;
    }
    __syncthreads();
    if (t == 0) {
        double* o = part + (size_t)blk * 4;
        o[0] = red[0] + red[3] + red[6] + red[9];
        o[1] = red[1] + red[4] + red[7] + red[10];
        o[2] = red[2] + red[5] + red[8] + red[11];
        __threadfence();                                       // release
        const unsigned prev = __hip_atomic_fetch_add(
            cnt, 1u, __ATOMIC_ACQ_REL, __HIP_MEMORY_SCOPE_AGENT);
        lastFlag = (prev == (unsigned)(gridDim.x - 1));
    }
    __syncthreads();

    // ---- last block combines (identical math regardless of which block) ----
    if (lastFlag) {
        __threadfence();                                       // acquire
        const int bb = t >> 3;
        const int l8 = t & 7;
        double sy = 0.0, sx = 0.0, sw = 0.0;
        #pragma unroll
        for (int k = l8; k < SPLIT; k += 8) {
            const double* o = part + (size_t)(bb * SPLIT + k) * 4;
            sy += o[0];
            sx += o[1];
            sw += o[2];
        }
        #pragma unroll
        for (int off = 1; off < 8; off <<= 1) {
            sy += __shfl_xor(sy, off);
            sx += __shfl_xor(sx, off);
            sw += __shfl_xor(sw, off);
        }
        if (l8 == 0) {
            // weighted_mean = (sy/sw, sx/sw) in (row, col); output is [::-1]
            out[bb * 2 + 0] = (float)(sx / sw);
            out[bb * 2 + 1] = (float)(sy / sw);
        }
    }
}

// ---------------- fallback path (round-4 proven): used if ws too small ----
__global__ __launch_bounds__(256, 4)
void hough_partial_fb(const float* __restrict__ uv,
                      const int* __restrict__ pts,
                      const int* __restrict__ pair,
                      double* __restrict__ part)
{
    const int blk = blockIdx.x;
    const int b = blk / SPLIT;
    const int s = blk % SPLIT;
    const int t = threadIdx.x;

    const float* uvb = uv + (size_t)b * CH * HH * WW;
    const int* ptsb = pts + b * PP * 2;

    __shared__ PtPack tile[TILE2];
    if (t < TILE2) {
        const int p = s * TILE + 2 * t;
        const int4 pp = *(const int4*)(ptsb + p * 2);
        const float u0 = uvb[pp.x * WW + pp.y];
        const float v0 = uvb[HH * WW + pp.x * WW + pp.y];
        const float u1 = uvb[pp.z * WW + pp.w];
        const float v1 = uvb[HH * WW + pp.z * WW + pp.w];
        const float c0 = (float)pp.x * u0 + (float)pp.y * v0;
        const float c1 = (float)pp.z * u1 + (float)pp.w * v1;
        PtPack pk;
        pk.u  = __floats2half2_rn(u0, u1);
        pk.v  = __floats2half2_rn(v0, v1);
        pk.nc = __floats2half2_rn(-c0, -c1);
        pk.pad = __floats2half2_rn(0.0f, 0.0f);
        tile[t] = pk;
    }

    const float2 Yn = solve_pair(uvb, ptsb, pair + b * NN * 2, t);
    const float yy = Yn.x, yx = Yn.y;
    const float maxab = fmaxf(fabsf(yy), fabsf(yx));
    const float sc = (maxab > 1024.0f) ? (1024.0f / maxab) : 1.0f;
    const __half2 yy2 = __float2half2_rn(yy * sc);
    const __half2 yx2 = __float2half2_rn(yx * sc);
    const __half2 sc2 = __float2half2_rn(sc);

    __syncthreads();

    unsigned negs = 0u;
    #pragma unroll 4
    for (int j = 0; j < TILE2; ++j) {
        const PtPack q = tile[j];
        __half2 d = __hmul2(yy2, q.u);
        d = __hfma2(yx2, q.v, d);
        d = __hfma2(sc2, q.nc, d);
        unsigned ub;
        __builtin_memcpy(&ub, &d, 4);
        negs += (ub >> 15) & 0x00010001u;
    }
    const int cw = TILE - (int)(negs & 0xFFFFu) - (int)(negs >> 16);

    double wy = (double)cw * (double)yy;
    double wx = (double)cw * (double)yx;
    double ww = (double)cw;
    #pragma unroll
    for (int off = 32; off > 0; off >>= 1) {
        wy += __shfl_down(wy, off);
        wx += __shfl_down(wx, off);
        ww += __shfl_down(ww, off);
    }
    __shared__ double red[4 * 3];
    const int wid = t >> 6;
    if ((t & 63) == 0) {
        red[wid * 3 + 0] = wy;
        red[wid * 3 + 1] = wx;
        red[wid * 3 + 2] = ww;
    }
    __syncthreads();
    if (t == 0) {
        double* o = part + (size_t)blk * 4;
        o[0] = red[0] + red[3] + red[6] + red[9];
        o[1] = red[1] + red[4] + red[7] + red[10];
        o[2] = red[2] + red[5] + red[8] + red[11];
    }
}

__global__ __launch_bounds__(256)
void hough_final_fb(const double* __restrict__ part, float* __restrict__ out)
{
    const int t = threadIdx.x;
    const int bb = t >> 3;
    const int l8 = t & 7;
    double sy = 0.0, sx = 0.0, sw = 0.0;
    #pragma unroll
    for (int k = l8; k < SPLIT; k += 8) {
        const double* o = part + (size_t)(bb * SPLIT + k) * 4;
        sy += o[0];
        sx += o[1];
        sw += o[2];
    }
    #pragma unroll
    for (int off = 1; off < 8; off <<= 1) {
        sy += __shfl_xor(sy, off);
        sx += __shfl_xor(sx, off);
        sw += __shfl_xor(sw, off);
    }
    if (l8 == 0) {
        out[bb * 2 + 0] = (float)(sx / sw);
        out[bb * 2 + 1] = (float)(sy / sw);
    }
}

extern "C" void kernel_launch(void* const* d_in, const int* in_sizes, int n_in,
                              void* d_out, int out_size, void* d_ws, size_t ws_size,
                              hipStream_t stream)
{
    const float* uv   = (const float*)d_in[0];   // (B, 2, 224, 224) f32
    const int*   pts  = (const int*)d_in[1];     // (B, 4096, 2) i32
    const int*   pair = (const int*)d_in[2];     // (B, 256, 2) i32
    float* out = (float*)d_out;                  // (B, 2) f32
    char* ws = (char*)d_ws;

    if (ws_size >= WS_NEED) {
        float2*   yv   = (float2*)(ws + WS_Y_OFF);
        double*   part = (double*)(ws + WS_PART_OFF);
        unsigned* cnt  = (unsigned*)(ws + WS_CNT_OFF);
        hough_solve<<<BATCH, 256, 0, stream>>>(uv, pts, pair, yv, cnt);
        hough_vote<<<BATCH * SPLIT, 256, 0, stream>>>(uv, pts, yv, part, cnt, out);
    } else {
        double* part = (double*)ws;              // 32 KB
        hough_partial_fb<<<BATCH * SPLIT, 256, 0, stream>>>(uv, pts, pair, part);
        hough_final_fb<<<1, 256, 0, stream>>>(part, out);
    }
}

// Round 6
// 20.378 us; speedup vs baseline: 2.3990x; 2.3990x over previous
//
#include <hip/hip_runtime.h>
#include <hip/hip_fp16.h>

// Problem constants (match reference)
#define BATCH 32
#define CH    2
#define HH    224
#define WW    224
#define PP    4096
#define NN    256
#define SPLIT 32
#define TILE  (PP / SPLIT)   // 128 points per block
#define TILE2 (TILE / 2)     // 64 packed point-pairs

// ws layout (fast path): [0,64K) float2 Y[B*N]; [64K,96K) part[1024*4] dbl.
#define WS_Y_OFF    0
#define WS_PART_OFF (64 * 1024)
#define WS_NEED     (96 * 1024)

// Packed vote-point pair: (u0,u1),(v0,v1),(-c0,-c1) in f16, padded to 16B so
// the vote loop reads one ds_read_b128 (broadcast) per TWO points.
// c = py*u + px*v, so agree = sign(yy*u + yx*v - c)  (the reference's
// normalization can't flip the sign, so the norm is dropped).
struct alignas(16) PtPack { __half2 u, v, nc, pad; };

// ---- shared solve: 2x2 pinv (f64, matches jnp.linalg.pinv semantics) ----
__device__ inline float2 solve_pair(const float* __restrict__ uvb,
                                    const int* __restrict__ ptsb,
                                    const int* __restrict__ pairb, int n)
{
    const int2 pr = *(const int2*)(pairb + n * 2);
    const int2 p0 = *(const int2*)(ptsb + pr.x * 2);
    const int2 p1 = *(const int2*)(ptsb + pr.y * 2);
    const int y0 = p0.x, x0 = p0.y;
    const int y1 = p1.x, x1 = p1.y;

    const float u0a = uvb[y0 * WW + x0];                 // uv[0] at pt0
    const float u0b = uvb[HH * WW + y0 * WW + x0];       // uv[1] at pt0
    const float u1a = uvb[y1 * WW + x1];                 // uv[0] at pt1
    const float u1b = uvb[HH * WW + y1 * WW + x1];       // uv[1] at pt1

    const double a00 = (double)u0a, a01 = -(double)u1a;
    const double a10 = (double)u0b, a11 = -(double)u1b;
    const double b0 = (double)(y1 - y0), b1 = (double)(x1 - x0);
    const double det = a00 * a11 - a01 * a10;
    const double frob2 = a00 * a00 + a01 * a01 + a10 * a10 + a11 * a11;

    double t0;
    if (fabs(det) > 1e-12 * frob2) {
        t0 = (b0 * a11 - b1 * a01) / det;          // first row of A^{-1} b
    } else if (frob2 > 0.0) {
        t0 = (a00 * b0 + a10 * b1) / frob2;        // rank-1 pinv: A^T b / ||A||_F^2
    } else {
        t0 = 0.0;
    }
    return make_float2((float)(t0 * (double)u0a + (double)y0),   // row
                       (float)(t0 * (double)u0b + (double)x0));  // col
}

// Kernel 1: solve every (b,n) ONCE. 32 blocks x 256 threads, coalesced
// float2 output to ws. No atomics, no fences.
__global__ __launch_bounds__(256)
void hough_solve(const float* __restrict__ uv,
                 const int* __restrict__ pts,
                 const int* __restrict__ pair,
                 float2* __restrict__ yv)
{
    const int b = blockIdx.x;
    const int t = threadIdx.x;
    const float* uvb = uv + (size_t)b * CH * HH * WW;
    yv[b * NN + t] = solve_pair(uvb, pts + b * PP * 2, pair + b * NN * 2, t);
}

// Kernel 2: one block per (batch, point-tile). 256 threads, one per pair n.
//   1. stage TILE points as f16 PtPacks in LDS
//   2. read Y (coalesced 8B), rescale into f16-safe range
//   3. packed-f16 vote, sign-bit counting
//   4. wave-shuffle reduce -> per-block partial. Nothing else.
__global__ __launch_bounds__(256, 4)
void hough_vote(const float* __restrict__ uv,
                const int* __restrict__ pts,
                const float2* __restrict__ yv,
                double* __restrict__ part)
{
    const int blk = blockIdx.x;
    const int b = blk / SPLIT;
    const int s = blk % SPLIT;
    const int t = threadIdx.x;   // n = t

    const float* uvb = uv + (size_t)b * CH * HH * WW;
    const int* ptsb = pts + b * PP * 2;

    // ---- stage this block's point tile in LDS (f16-packed, 2 pts / 16B) ----
    __shared__ PtPack tile[TILE2];
    if (t < TILE2) {
        const int p = s * TILE + 2 * t;
        const int4 pp = *(const int4*)(ptsb + p * 2);   // (y0,x0,y1,x1), 16B
        const float u0 = uvb[pp.x * WW + pp.y];
        const float v0 = uvb[HH * WW + pp.x * WW + pp.y];
        const float u1 = uvb[pp.z * WW + pp.w];
        const float v1 = uvb[HH * WW + pp.z * WW + pp.w];
        const float c0 = (float)pp.x * u0 + (float)pp.y * v0;
        const float c1 = (float)pp.z * u1 + (float)pp.w * v1;
        PtPack pk;
        pk.u  = __floats2half2_rn(u0, u1);
        pk.v  = __floats2half2_rn(v0, v1);
        pk.nc = __floats2half2_rn(-c0, -c1);
        pk.pad = __floats2half2_rn(0.0f, 0.0f);
        tile[t] = pk;
    }

    // ---- read precomputed Y, scale (yy, yx, 1) into f16-safe range ----
    const float2 Yn = yv[b * NN + t];
    const float yy = Yn.x, yx = Yn.y;
    const float maxab = fmaxf(fabsf(yy), fabsf(yx));
    const float sc = (maxab > 1024.0f) ? (1024.0f / maxab) : 1.0f;
    const __half2 yy2 = __float2half2_rn(yy * sc);
    const __half2 yx2 = __float2half2_rn(yx * sc);
    const __half2 sc2 = __float2half2_rn(sc);

    __syncthreads();

    // ---- voting: packed f16, 2 points per iteration, sign-bit counting ----
    unsigned negs = 0u;
    #pragma unroll 4
    for (int j = 0; j < TILE2; ++j) {
        const PtPack q = tile[j];                  // broadcast ds_read_b128
        __half2 d = __hmul2(yy2, q.u);
        d = __hfma2(yx2, q.v, d);
        d = __hfma2(sc2, q.nc, d);
        unsigned ub;
        __builtin_memcpy(&ub, &d, 4);
        negs += (ub >> 15) & 0x00010001u;          // sign bits of both halves
    }
    const int cw = TILE - (int)(negs & 0xFFFFu) - (int)(negs >> 16);

    // ---- deterministic reduction of (w*Yy, w*Yx, w) ----
    double wy = (double)cw * (double)yy;
    double wx = (double)cw * (double)yx;
    double ww = (double)cw;
    #pragma unroll
    for (int off = 32; off > 0; off >>= 1) {
        wy += __shfl_down(wy, off);
        wx += __shfl_down(wx, off);
        ww += __shfl_down(ww, off);
    }

    __shared__ double red[4 * 3];
    const int wid = t >> 6;
    if ((t & 63) == 0) {
        red[wid * 3 + 0] = wy;
        red[wid * 3 + 1] = wx;
        red[wid * 3 + 2] = ww;
    }
    __syncthreads();
    if (t == 0) {
        double* o = part + (size_t)blk * 4;
        o[0] = red[0] + red[3] + red[6] + red[9];
        o[1] = red[1] + red[4] + red[7] + red[10];
        o[2] = red[2] + red[5] + red[8] + red[11];
    }
}

// Kernel 3: combine the SPLIT partials per batch, divide, write reversed out.
// 256 threads = 32 batches x 8 lanes; each lane sums 4 partials, then a
// 3-step shfl_xor butterfly within the aligned 8-lane group (deterministic).
__global__ __launch_bounds__(256)
void hough_final(const double* __restrict__ part, float* __restrict__ out)
{
    const int t = threadIdx.x;
    const int bb = t >> 3;
    const int l8 = t & 7;
    double sy = 0.0, sx = 0.0, sw = 0.0;
    #pragma unroll
    for (int k = l8; k < SPLIT; k += 8) {
        const double* o = part + (size_t)(bb * SPLIT + k) * 4;
        sy += o[0];
        sx += o[1];
        sw += o[2];
    }
    #pragma unroll
    for (int off = 1; off < 8; off <<= 1) {
        sy += __shfl_xor(sy, off);
        sx += __shfl_xor(sx, off);
        sw += __shfl_xor(sw, off);
    }
    if (l8 == 0) {
        // weighted_mean = (sy/sw, sx/sw) in (row, col); output is [::-1]
        out[bb * 2 + 0] = (float)(sx / sw);
        out[bb * 2 + 1] = (float)(sy / sw);
    }
}

// ---------------- fallback (round-4 proven, solve-in-block) ----------------
__global__ __launch_bounds__(256, 4)
void hough_partial_fb(const float* __restrict__ uv,
                      const int* __restrict__ pts,
                      const int* __restrict__ pair,
                      double* __restrict__ part)
{
    const int blk = blockIdx.x;
    const int b = blk / SPLIT;
    const int s = blk % SPLIT;
    const int t = threadIdx.x;

    const float* uvb = uv + (size_t)b * CH * HH * WW;
    const int* ptsb = pts + b * PP * 2;

    __shared__ PtPack tile[TILE2];
    if (t < TILE2) {
        const int p = s * TILE + 2 * t;
        const int4 pp = *(const int4*)(ptsb + p * 2);
        const float u0 = uvb[pp.x * WW + pp.y];
        const float v0 = uvb[HH * WW + pp.x * WW + pp.y];
        const float u1 = uvb[pp.z * WW + pp.w];
        const float v1 = uvb[HH * WW + pp.z * WW + pp.w];
        const float c0 = (float)pp.x * u0 + (float)pp.y * v0;
        const float c1 = (float)pp.z * u1 + (float)pp.w * v1;
        PtPack pk;
        pk.u  = __floats2half2_rn(u0, u1);
        pk.v  = __floats2half2_rn(v0, v1);
        pk.nc = __floats2half2_rn(-c0, -c1);
        pk.pad = __floats2half2_rn(0.0f, 0.0f);
        tile[t] = pk;
    }

    const float2 Yn = solve_pair(uvb, ptsb, pair + b * NN * 2, t);
    const float yy = Yn.x, yx = Yn.y;
    const float maxab = fmaxf(fabsf(yy), fabsf(yx));
    const float sc = (maxab > 1024.0f) ? (1024.0f / maxab) : 1.0f;
    const __half2 yy2 = __float2half2_rn(yy * sc);
    const __half2 yx2 = __float2half2_rn(yx * sc);
    const __half2 sc2 = __float2half2_rn(sc);

    __syncthreads();

    unsigned negs = 0u;
    #pragma unroll 4
    for (int j = 0; j < TILE2; ++j) {
        const PtPack q = tile[j];
        __half2 d = __hmul2(yy2, q.u);
        d = __hfma2(yx2, q.v, d);
        d = __hfma2(sc2, q.nc, d);
        unsigned ub;
        __builtin_memcpy(&ub, &d, 4);
        negs += (ub >> 15) & 0x00010001u;
    }
    const int cw = TILE - (int)(negs & 0xFFFFu) - (int)(negs >> 16);

    double wy = (double)cw * (double)yy;
    double wx = (double)cw * (double)yx;
    double ww = (double)cw;
    #pragma unroll
    for (int off = 32; off > 0; off >>= 1) {
        wy += __shfl_down(wy, off);
        wx += __shfl_down(wx, off);
        ww += __shfl_down(ww, off);
    }
    __shared__ double red[4 * 3];
    const int wid = t >> 6;
    if ((t & 63) == 0) {
        red[wid * 3 + 0] = wy;
        red[wid * 3 + 1] = wx;
        red[wid * 3 + 2] = ww;
    }
    __syncthreads();
    if (t == 0) {
        double* o = part + (size_t)blk * 4;
        o[0] = red[0] + red[3] + red[6] + red[9];
        o[1] = red[1] + red[4] + red[7] + red[10];
        o[2] = red[2] + red[5] + red[8] + red[11];
    }
}

extern "C" void kernel_launch(void* const* d_in, const int* in_sizes, int n_in,
                              void* d_out, int out_size, void* d_ws, size_t ws_size,
                              hipStream_t stream)
{
    const float* uv   = (const float*)d_in[0];   // (B, 2, 224, 224) f32
    const int*   pts  = (const int*)d_in[1];     // (B, 4096, 2) i32
    const int*   pair = (const int*)d_in[2];     // (B, 256, 2) i32
    float* out = (float*)d_out;                  // (B, 2) f32
    char* ws = (char*)d_ws;

    if (ws_size >= WS_NEED) {
        float2* yv   = (float2*)(ws + WS_Y_OFF);
        double* part = (double*)(ws + WS_PART_OFF);
        hough_solve<<<BATCH, 256, 0, stream>>>(uv, pts, pair, yv);
        hough_vote<<<BATCH * SPLIT, 256, 0, stream>>>(uv, pts, yv, part);
        hough_final<<<1, 256, 0, stream>>>(part, out);
    } else {
        double* part = (double*)ws;              // 32 KB
        hough_partial_fb<<<BATCH * SPLIT, 256, 0, stream>>>(uv, pts, pair, part);
        hough_final<<<1, 256, 0, stream>>>(part, out);
    }
}